// Round 16
// baseline (140.668 us; speedup 1.0000x reference)
//
#include <hip/hip_runtime.h>
#include <stdint.h>
#include <stddef.h>

// ---- problem constants ----
#define K_CODES 1024
#define D_DIM   256
#define HW      1024      // 32*32 spatial
#define N_VEC   32768
#define TOT_ELEMS 8388608
#define NBLK    256       // vq_main grid

typedef float    v4f __attribute__((ext_vector_type(4)));
typedef _Float16 v8h __attribute__((ext_vector_type(8)));

// async global->LDS, 16B/lane, dest = wave-uniform base + lane*16
__device__ __forceinline__ void gld_lds16(const void* g, void* l) {
    __builtin_amdgcn_global_load_lds(
        (const __attribute__((address_space(1))) void*)g,
        (__attribute__((address_space(3))) void*)l, 16, 0, 0);
}

// ------------------------------------------------------------------
// K1: codebook -> fp16 copy + 0.5*||e||^2 (+ zero loss_acc & counter,
// replacing the old hipMemsetAsync graph node).
__global__ void prep_emb(const float* __restrict__ emb,
                         _Float16* __restrict__ emb_h,
                         float* __restrict__ hnorm,
                         float* __restrict__ loss_acc,
                         unsigned* __restrict__ cnt) {
    int k = blockIdx.x, t = threadIdx.x;
    if (k == 0 && t == 0) { loss_acc[0] = 0.f; cnt[0] = 0u; }
    float v = emb[(size_t)k * D_DIM + t];
    emb_h[(size_t)k * D_DIM + t] = (_Float16)v;
    float s = v * v;
    for (int off = 32; off; off >>= 1) s += __shfl_down(s, off);
    __shared__ float wsum[4];
    if ((t & 63) == 0) wsum[t >> 6] = s;
    __syncthreads();
    if (t == 0) hnorm[k] = 0.5f * (wsum[0] + wsum[1] + wsum[2] + wsum[3]);
}

// ------------------------------------------------------------------
// K2: fused VQ — R12 structure (verified: 52.3us, VGPR 88, no spill,
// FETCH 24 MB) with ONE change: 32-code tiles (btile 128->64 KB,
// LDS ~71.4 KB) so 2 blocks/CU can co-reside (R3 proved 2-block
// residency at ~71 KB LDS). Work totals identical: 2048 ds_read_b128
// + 4096 MFMA per block, 256 blocks, 128 rows/block, 2-way K-split,
// same swizzle u = g ^ (k&7) (k&7 == col&7 holds for 32-code tiles),
// ascending code order + strict < => bit-identical argmin. Cost: 16
// barriers (was 8). launch_bounds (512,4): cap 128 regs >= 88 used.
// Grafts kept: loss-from-argmin (no epilogue z re-read), finalize via
// last-block ticket.
__global__ __launch_bounds__(512, 4) void
vq_main(const float* __restrict__ z,
        const _Float16* __restrict__ emb_h,
        const float* __restrict__ emb,
        const float* __restrict__ hnorm,
        float* __restrict__ out,
        float* __restrict__ loss_acc,
        unsigned* __restrict__ cnt) {
    // btile: [2 grp][2 buf][16 KB] = 64 KB; epilogue zq overlays
    // (2 grp x 32 rows x 257 floats = 65792 B).
    __shared__ __align__(16) char smem[66048];
    __shared__ float  norm_s[K_CODES];
    __shared__ int    idx_s[128];
    __shared__ float2 mrg[4][32];
    __shared__ float  wred[4];

    _Float16* btile = (_Float16*)smem;

    int t    = threadIdx.x;
    int wave = t >> 6;
    int lane = t & 63;
    int grp  = wave >> 2;     // K-half (512 codes each)
    int wv   = wave & 3;      // row-tile selector
    int col  = lane & 15;
    int quad = lane >> 4;
    int b    = blockIdx.x >> 3;
    int hw0  = (blockIdx.x & 7) * 128;
    const float* zb = z + (size_t)b * D_DIM * HW;

    // stage tile T (32 codes, 16 KB) of this wave's K-half; the four
    // waves sharing a half (wv 0..3) each stage 8 codes (4 KB).
    auto stage = [&](int buf, int T) {
        const char* src = (const char*)(emb_h
                          + (size_t)(grp * 512 + T * 32) * D_DIM);
        char* dst = (char*)(btile + (size_t)(grp * 2 + buf) * 8192)
                    + wv * 4096;
#pragma unroll
        for (int i = 0; i < 4; ++i) {
            int k = wv * 8 + i * 2 + (lane >> 5);
            int g = (lane & 31) ^ (k & 7);
            gld_lds16(src + (size_t)k * 512 + (size_t)g * 16, dst + i * 1024);
        }
    };
    stage(0, 0);

    for (int i = t; i < K_CODES; i += 512) norm_s[i] = hnorm[i];

    // A fragments (32 rows/wave, both K-halves load same rows) + fp32
    // row-norm partials for the fused loss.
    int m0w = hw0 + wv * 32;
    v8h af0[8], af1[8];
    float z2a = 0.f, z2b = 0.f;
#pragma unroll
    for (int c = 0; c < 8; ++c) {
#pragma unroll
        for (int j = 0; j < 8; ++j) {
            int d = c * 32 + quad * 8 + j;
            const float* p = zb + (size_t)d * HW + m0w + col;
            float v0 = p[0], v1 = p[16];
            af0[c][j] = (_Float16)v0;
            af1[c][j] = (_Float16)v1;
            z2a += v0 * v0;
            z2b += v1 * v1;
        }
    }
    // lanes col, col+16, col+32, col+48 all end with full norm of row m0w+col
    z2a += __shfl_xor(z2a, 16); z2a += __shfl_xor(z2a, 32);
    z2b += __shfl_xor(z2b, 16); z2b += __shfl_xor(z2b, 32);

    float minv[8]; int mini[8];
#pragma unroll
    for (int r = 0; r < 8; ++r) { minv[r] = 3.4e38f; mini[r] = 0; }

    for (int T = 0; T < 16; ++T) {
        __syncthreads();                 // staged buffer ready
        if (T < 15) stage((T + 1) & 1, T + 1);
        const _Float16* bt = btile + (size_t)(grp * 2 + (T & 1)) * 8192;
#pragma unroll
        for (int cc = 0; cc < 2; ++cc) {
            int k = cc * 16 + col;
            v8h bf[8];
#pragma unroll
            for (int c = 0; c < 8; ++c) {
                int u = (c * 4 + quad) ^ (col & 7);   // k&7 == col&7
                bf[c] = *(const v8h*)(bt + (size_t)k * D_DIM + (u << 3));
            }
            v4f acc0 = {0.f, 0.f, 0.f, 0.f};
            v4f acc1 = {0.f, 0.f, 0.f, 0.f};
#pragma unroll
            for (int c = 0; c < 8; ++c) {
                acc0 = __builtin_amdgcn_mfma_f32_16x16x32_f16(af0[c], bf[c], acc0, 0, 0, 0);
                acc1 = __builtin_amdgcn_mfma_f32_16x16x32_f16(af1[c], bf[c], acc1, 0, 0, 0);
            }
            int   code = grp * 512 + T * 32 + k;
            float n    = norm_s[code];
#pragma unroll
            for (int r = 0; r < 4; ++r) {
                float d0 = n - acc0[r];
                if (d0 < minv[r])     { minv[r]     = d0; mini[r]     = code; }
                float d1 = n - acc1[r];
                if (d1 < minv[4 + r]) { minv[4 + r] = d1; mini[4 + r] = code; }
            }
        }
    }
    // reduce across the 16 cols of each quad
#pragma unroll
    for (int off = 1; off < 16; off <<= 1) {
#pragma unroll
        for (int r = 0; r < 8; ++r) {
            float ov = __shfl_xor(minv[r], off);
            int   oi = __shfl_xor(mini[r], off);
            if (ov < minv[r] || (ov == minv[r] && oi < mini[r])) {
                minv[r] = ov; mini[r] = oi;
            }
        }
    }
    // K-split merge: half-1 posts, half-0 merges (strict < keeps low
    // idx) + computes the fused loss from the winning min value.
    if (grp == 1 && col == 0) {
#pragma unroll
        for (int r = 0; r < 8; ++r) {
            int rl = (r >> 2) * 16 + quad * 4 + (r & 3);
            mrg[wv][rl] = make_float2(minv[r], __int_as_float(mini[r]));
        }
    }
    __syncthreads();
    if (grp == 0) {
        // full row-norms for this wave's rows (r 0..3: af0 rows
        // quad*4+r; r 4..7: af1 rows 16+quad*4+(r&3))
        float z2r[8];
#pragma unroll
        for (int r = 0; r < 4; ++r) {
            z2r[r]     = __shfl(z2a, quad * 4 + r);
            z2r[4 + r] = __shfl(z2b, quad * 4 + r);
        }
        float lsum = 0.f;
        if (col == 0) {
#pragma unroll
            for (int r = 0; r < 8; ++r) {
                int rl = (r >> 2) * 16 + quad * 4 + (r & 3);
                float2 m2 = mrg[wv][rl];
                float bv = minv[r]; int bi = mini[r];
                if (m2.x < bv) { bv = m2.x; bi = __float_as_int(m2.y); }
                idx_s[wv * 32 + rl] = bi;
                // ||z-e||^2 = ||z||^2 + 2*(0.5||e||^2 - <z,e>)
                lsum += z2r[r] + 2.f * bv;
            }
        }
        lsum += __shfl_xor(lsum, 16);
        lsum += __shfl_xor(lsum, 32);
        if (lane == 0) wred[wv] = lsum;
    }
    __syncthreads();

    // ---- epilogue: gather emb rows -> LDS, write out (no z re-read) --
    // group g handles rows hw0 + g*64 .. +63 in two 32-row passes
    float* zqg = (float*)smem + grp * 8224;   // 32 x 257 floats
    int tt = t & 255;
    for (int s = 0; s < 2; ++s) {
        if (s) __syncthreads();
#pragma unroll 4
        for (int i = 0; i < 32; ++i)
            zqg[i * 257 + tt] =
                emb[(size_t)idx_s[grp * 64 + s * 32 + i] * D_DIM + tt];
        __syncthreads();
        int j = tt & 31, dq = tt >> 5;
#pragma unroll 4
        for (int p = 0; p < 32; ++p) {
            int d = dq * 32 + p;
            size_t o = (size_t)(b * D_DIM + d) * HW
                       + hw0 + grp * 64 + s * 32 + j;
            out[o] = zqg[j * 257 + d];        // z_q_st == z_q numerically
        }
    }
    if (t == 0) {
        float s4 = wred[0] + wred[1] + wred[2] + wred[3];
        atomicAdd(loss_acc, s4);
        __threadfence();
        if (atomicAdd(cnt, 1u) == NBLK - 1) {
            // all blocks' loss adds are visible at the L2 atomic point
            float total = atomicAdd(loss_acc, 0.0f);
            out[TOT_ELEMS] = total * (1.25f / (float)TOT_ELEMS);
        }
    }
}

// ------------------------------------------------------------------
extern "C" void kernel_launch(void* const* d_in, const int* in_sizes, int n_in,
                              void* d_out, int out_size, void* d_ws, size_t ws_size,
                              hipStream_t stream) {
    const float* z   = (const float*)d_in[0];   // [32,256,32,32]
    const float* emb = (const float*)d_in[1];   // [1024,256]
    float* out = (float*)d_out;                 // [8388608 z_q_st][1 loss]

    char* ws = (char*)d_ws;
    float*    loss_acc = (float*)ws;            // @0
    unsigned* cnt      = (unsigned*)(ws + 4);   // last-block ticket
    float*    hnorm    = (float*)(ws + 1024);   // 4 KB
    _Float16* emb_h    = (_Float16*)(ws + 8192);// 512 KB

    prep_emb<<<dim3(K_CODES), dim3(256), 0, stream>>>(emb, emb_h, hnorm,
                                                      loss_acc, cnt);
    vq_main<<<dim3(NBLK), dim3(512), 0, stream>>>(z, emb_h, emb, hnorm,
                                                  out, loss_acc, cnt);
}

// Round 17
// 135.062 us; speedup vs baseline: 1.0415x; 1.0415x over previous
//
#include <hip/hip_runtime.h>
#include <stdint.h>
#include <stddef.h>

// ---- problem constants ----
#define K_CODES 1024
#define D_DIM   256
#define HW      1024      // 32*32 spatial
#define N_VEC   32768
#define TOT_ELEMS 8388608
#define NBLK    256       // vq_main grid

typedef float    v4f __attribute__((ext_vector_type(4)));
typedef _Float16 v8h __attribute__((ext_vector_type(8)));

// async global->LDS, 16B/lane, dest = wave-uniform base + lane*16
__device__ __forceinline__ void gld_lds16(const void* g, void* l) {
    __builtin_amdgcn_global_load_lds(
        (const __attribute__((address_space(1))) void*)g,
        (__attribute__((address_space(3))) void*)l, 16, 0, 0);
}

// ------------------------------------------------------------------
// K1: codebook -> fp16 copy + 0.5*||e||^2 (+ zero loss_acc & counter).
__global__ void prep_emb(const float* __restrict__ emb,
                         _Float16* __restrict__ emb_h,
                         float* __restrict__ hnorm,
                         float* __restrict__ loss_acc,
                         unsigned* __restrict__ cnt) {
    int k = blockIdx.x, t = threadIdx.x;
    if (k == 0 && t == 0) { loss_acc[0] = 0.f; cnt[0] = 0u; }
    float v = emb[(size_t)k * D_DIM + t];
    emb_h[(size_t)k * D_DIM + t] = (_Float16)v;
    float s = v * v;
    for (int off = 32; off; off >>= 1) s += __shfl_down(s, off);
    __shared__ float wsum[4];
    if ((t & 63) == 0) wsum[t >> 6] = s;
    __syncthreads();
    if (t == 0) hnorm[k] = 0.5f * (wsum[0] + wsum[1] + wsum[2] + wsum[3]);
}

// ------------------------------------------------------------------
// K2: fused VQ — champion R0 main loop VERBATIM (proven 49.5us: 256
// blocks x 512 thr, 128 rows, 2-way K-split, 64-code dbuf tiles,
// swizzle u = g ^ (k&7), VGPR ~90, 2 waves/SIMD — the reg-arithmetic
// wall: full reuse needs ~137 regs, so >2 waves/SIMD is impossible
// without spill (R8/R16) or reuse loss (R3/R4); grid=CU count makes
// LDS-shrink moot (R16)). Grafts, now overhead-free:
//  (1) loss = SUM(||z||^2) + 2*SUM(minv_win): per-thread private z2
//      accumulation in the A-prologue (grp0 threads cover every z
//      element exactly once — NO shuffles), merge adds 2*bv, one
//      block-reduce + atomic. Epilogue z re-read/MSE deleted
//      (R12-verified: FETCH -9 MB, absmax unchanged).
//  (2) finalize folded via last-block ticket (2-node graph).
__global__ __launch_bounds__(512, 2) void
vq_main(const float* __restrict__ z,
        const _Float16* __restrict__ emb_h,
        const float* __restrict__ emb,
        const float* __restrict__ hnorm,
        float* __restrict__ out,
        float* __restrict__ loss_acc,
        unsigned* __restrict__ cnt) {
    __shared__ __align__(16) char smem[131072];   // btile[2grp][2buf][32KB] / zq
    __shared__ float  norm_s[K_CODES];
    __shared__ int    idx_s[128];
    __shared__ float2 mrg[4][32];
    __shared__ float  wred[8];

    _Float16* btile = (_Float16*)smem;

    int t    = threadIdx.x;
    int wave = t >> 6;
    int lane = t & 63;
    int grp  = wave >> 2;     // K-half
    int wv   = wave & 3;      // row-tile selector
    int col  = lane & 15;
    int quad = lane >> 4;
    int b    = blockIdx.x >> 3;
    int hw0  = (blockIdx.x & 7) * 128;
    const float* zb = z + (size_t)b * D_DIM * HW;

    // stage tile T (64 codes, 32 KB) of this wave's K-half
    auto stage = [&](int buf, int T) {
        const char* src = (const char*)(emb_h
                          + (size_t)(grp * 512 + T * 64) * D_DIM);
        char* dst = (char*)(btile + (size_t)(grp * 2 + buf) * 16384)
                    + wv * 8192;
#pragma unroll
        for (int i = 0; i < 8; ++i) {
            int k = wv * 16 + i * 2 + (lane >> 5);
            int g = (lane & 31) ^ (k & 7);
            gld_lds16(src + (size_t)k * 512 + (size_t)g * 16, dst + i * 1024);
        }
    };
    stage(0, 0);

    for (int i = t; i < K_CODES; i += 512) norm_s[i] = hnorm[i];

    // A fragments (32 rows/wave, both K-halves load same rows).
    // grp==0's 256 threads collectively touch every z element of this
    // block's slice exactly once -> private z2 partials give SUM(||z||^2)
    // with zero cross-lane traffic.
    int m0w = hw0 + wv * 32;
    v8h af0[8], af1[8];
    float z2 = 0.f;
#pragma unroll
    for (int c = 0; c < 8; ++c) {
#pragma unroll
        for (int j = 0; j < 8; ++j) {
            int d = c * 32 + quad * 8 + j;
            const float* p = zb + (size_t)d * HW + m0w + col;
            float v0 = p[0], v1 = p[16];
            af0[c][j] = (_Float16)v0;
            af1[c][j] = (_Float16)v1;
            z2 += v0 * v0 + v1 * v1;
        }
    }

    float minv[8]; int mini[8];
#pragma unroll
    for (int r = 0; r < 8; ++r) { minv[r] = 3.4e38f; mini[r] = 0; }

    for (int T = 0; T < 8; ++T) {
        __syncthreads();                 // staged buffer ready
        if (T < 7) stage((T + 1) & 1, T + 1);
        const _Float16* bt = btile + (size_t)(grp * 2 + (T & 1)) * 16384;
#pragma unroll
        for (int cc = 0; cc < 4; ++cc) {
            int k = cc * 16 + col;
            v8h bf[8];
#pragma unroll
            for (int c = 0; c < 8; ++c) {
                int u = (c * 4 + quad) ^ (col & 7);   // k&7 == col&7
                bf[c] = *(const v8h*)(bt + (size_t)k * D_DIM + (u << 3));
            }
            v4f acc0 = {0.f, 0.f, 0.f, 0.f};
            v4f acc1 = {0.f, 0.f, 0.f, 0.f};
#pragma unroll
            for (int c = 0; c < 8; ++c) {
                acc0 = __builtin_amdgcn_mfma_f32_16x16x32_f16(af0[c], bf[c], acc0, 0, 0, 0);
                acc1 = __builtin_amdgcn_mfma_f32_16x16x32_f16(af1[c], bf[c], acc1, 0, 0, 0);
            }
            int   code = grp * 512 + T * 64 + k;
            float n    = norm_s[code];
#pragma unroll
            for (int r = 0; r < 4; ++r) {
                float d0 = n - acc0[r];
                if (d0 < minv[r])     { minv[r]     = d0; mini[r]     = code; }
                float d1 = n - acc1[r];
                if (d1 < minv[4 + r]) { minv[4 + r] = d1; mini[4 + r] = code; }
            }
        }
    }
    // reduce across the 16 cols of each quad
#pragma unroll
    for (int off = 1; off < 16; off <<= 1) {
#pragma unroll
        for (int r = 0; r < 8; ++r) {
            float ov = __shfl_xor(minv[r], off);
            int   oi = __shfl_xor(mini[r], off);
            if (ov < minv[r] || (ov == minv[r] && oi < mini[r])) {
                minv[r] = ov; mini[r] = oi;
            }
        }
    }
    // K-split merge: half-1 posts, half-0 merges (strict < keeps low
    // idx). Winning min value feeds the loss: 2*bv per row.
    if (grp == 1 && col == 0) {
#pragma unroll
        for (int r = 0; r < 8; ++r) {
            int rl = (r >> 2) * 16 + quad * 4 + (r & 3);
            mrg[wv][rl] = make_float2(minv[r], __int_as_float(mini[r]));
        }
    }
    __syncthreads();
    float lsum = (grp == 0) ? z2 : 0.f;   // SUM(||z||^2) contribution
    if (grp == 0 && col == 0) {
#pragma unroll
        for (int r = 0; r < 8; ++r) {
            int rl = (r >> 2) * 16 + quad * 4 + (r & 3);
            float2 m2 = mrg[wv][rl];
            float bv = minv[r]; int bi = mini[r];
            if (m2.x < bv) { bv = m2.x; bi = __float_as_int(m2.y); }
            idx_s[wv * 32 + rl] = bi;
            // ||z-e||^2 = ||z||^2 + 2*(0.5||e||^2 - <z,e>)
            lsum += 2.f * bv;
        }
    }
    // block loss reduction (all waves; grp1 contributes 0)
    for (int off = 32; off; off >>= 1) lsum += __shfl_down(lsum, off);
    if (lane == 0) wred[wave] = lsum;
    __syncthreads();

    // ---- epilogue: gather emb rows -> LDS, write out (no z re-read) --
    // group g handles rows hw0 + g*64 .. +63 in two 32-row passes
    float* zqg = (float*)smem + grp * 8224;   // 32 x 257 floats
    int tt = t & 255;
    for (int s = 0; s < 2; ++s) {
        if (s) __syncthreads();
#pragma unroll 4
        for (int i = 0; i < 32; ++i)
            zqg[i * 257 + tt] =
                emb[(size_t)idx_s[grp * 64 + s * 32 + i] * D_DIM + tt];
        __syncthreads();
        int j = tt & 31, dq = tt >> 5;
#pragma unroll 4
        for (int p = 0; p < 32; ++p) {
            int d = dq * 32 + p;
            size_t o = (size_t)(b * D_DIM + d) * HW
                       + hw0 + grp * 64 + s * 32 + j;
            out[o] = zqg[j * 257 + d];        // z_q_st == z_q numerically
        }
    }
    if (t == 0) {
        float s8 = 0.f;
#pragma unroll
        for (int i = 0; i < 8; ++i) s8 += wred[i];
        atomicAdd(loss_acc, s8);
        __threadfence();
        if (atomicAdd(cnt, 1u) == NBLK - 1) {
            // all blocks' loss adds are visible at the L2 atomic point
            float total = atomicAdd(loss_acc, 0.0f);
            out[TOT_ELEMS] = total * (1.25f / (float)TOT_ELEMS);
        }
    }
}

// ------------------------------------------------------------------
extern "C" void kernel_launch(void* const* d_in, const int* in_sizes, int n_in,
                              void* d_out, int out_size, void* d_ws, size_t ws_size,
                              hipStream_t stream) {
    const float* z   = (const float*)d_in[0];   // [32,256,32,32]
    const float* emb = (const float*)d_in[1];   // [1024,256]
    float* out = (float*)d_out;                 // [8388608 z_q_st][1 loss]

    char* ws = (char*)d_ws;
    float*    loss_acc = (float*)ws;            // @0
    unsigned* cnt      = (unsigned*)(ws + 4);   // last-block ticket
    float*    hnorm    = (float*)(ws + 1024);   // 4 KB
    _Float16* emb_h    = (_Float16*)(ws + 8192);// 512 KB

    prep_emb<<<dim3(K_CODES), dim3(256), 0, stream>>>(emb, emb_h, hnorm,
                                                      loss_acc, cnt);
    vq_main<<<dim3(NBLK), dim3(512), 0, stream>>>(z, emb_h, emb, hnorm,
                                                  out, loss_acc, cnt);
}